// Round 4
// baseline (8728.499 us; speedup 1.0000x reference)
//
#include <hip/hip_runtime.h>
#include <hip/hip_bf16.h>
#include <cstdint>
#include <cstddef>

// B=128 T=96 D=256 H=256 C=8 M=64, COMB=1280
// combined = [z | zp | x_i | gd | h], gate interleave n=4j+g (g: i,f,o,c)
//   U [n][512]: k<256 -> W_h[j][k] + sum_d W_xi[j][d]*W_fc[d][k]; k>=256 -> W_gd
//   Uz[n][512]: W_g[j][0:512] (z|zp)
//   bias2[n]  : b_g[j] + sum_d W_xi[j][d]*b_fc[d]
// Inputs may be fp32 or bf16 (clusters int64 or int32) -> runtime-detected.
// OUTPUT dtype follows input float dtype (fp32 ref -> float* out).

#define PLANE 24576   // 96*256

using bf16_t = __hip_bfloat16;
typedef __bf16 bf16x8 __attribute__((ext_vector_type(8)));
typedef float  f32x4  __attribute__((ext_vector_type(4)));

__device__ __forceinline__ float  b2f(bf16_t v){ return __bfloat162float(v); }
__device__ __forceinline__ bf16_t f2b(float v){ return __float2bfloat16(v); }
__device__ __forceinline__ float ldF(const void* p, size_t i, int f32){
  return f32 ? ((const float*)p)[i] : b2f(((const bf16_t*)p)[i]);
}
__device__ __forceinline__ bf16x8 ld_frag(const void* p){
  union { uint4 u; bf16x8 v; } c;
  c.u = *(const uint4*)p;
  return c.v;
}
__device__ __forceinline__ f32x4 mfma_bf16(bf16x8 a, bf16x8 b, f32x4 c){
  return __builtin_amdgcn_mfma_f32_16x16x32_bf16(a, b, c, 0, 0, 0);
}

// ---------------- dtype detection ----------------
__global__ __launch_bounds__(64) void k_detect(
    const uint32_t* __restrict__ xu, const uint32_t* __restrict__ clu,
    int* __restrict__ flags)
{
  __shared__ int cnt[2];
  int t = threadIdx.x;
  if (t < 2) cnt[t] = 0;
  __syncthreads();
  // If x is fp32, words [2*PLANE,...) are Mask = exactly 0.0f / 1.0f.
  uint32_t v = xu[2*PLANE + t];
  if (v == 0u || v == 0x3F800000u) atomicAdd(&cnt[0], 1);
  // If clusters is int64, odd 32-bit words (high halves) are all 0.
  if (clu[2*t + 1] == 0u) atomicAdd(&cnt[1], 1);
  __syncthreads();
  if (t == 0){
    flags[0] = (cnt[0] >= 48) ? 1 : 0;   // 1 = float tensors are fp32
    flags[1] = (cnt[1] >= 60) ? 1 : 0;   // 1 = clusters is int64
  }
}

// ---------------- canonicalize small tensors to bf16/fp32 ws ----------------
__global__ __launch_bounds__(256) void k_canon(
    const void* __restrict__ Wfc, const void* __restrict__ Xmean,
    const void* __restrict__ bfc, const void* __restrict__ localw,
    const void* __restrict__ globalw, const void* __restrict__ gzw,
    const void* __restrict__ gzb, const void* __restrict__ gzpw,
    const void* __restrict__ gzpb, const int* __restrict__ flags,
    bf16_t* __restrict__ WfcC, bf16_t* __restrict__ XmC,
    bf16_t* __restrict__ bfcC, bf16_t* __restrict__ lwC,
    bf16_t* __restrict__ gwC, float* __restrict__ gzC)
{
  const int f32 = flags[0];
  int i = blockIdx.x*256 + threadIdx.x;
  if (i < 65536) WfcC[i] = f2b(ldF(Wfc, i, f32));
  if (i < 24576) XmC[i]  = f2b(ldF(Xmean, i, f32));
  if (i < 256)   bfcC[i] = f2b(ldF(bfc, i, f32));
  if (i < 768)   lwC[i]  = f2b(ldF(localw, i, f32));
  if (i < 8)     gwC[i]  = f2b(ldF(globalw, i, f32));
  if (i < 256){
    gzC[i]       = ldF(gzw,  i, f32);
    gzC[256 + i] = ldF(gzb,  i, f32);
    gzC[512 + i] = ldF(gzpw, i, f32);
    gzC[768 + i] = ldF(gzpb, i, f32);
  }
}

// ---------------- weight folding ----------------
__global__ __launch_bounds__(256) void k_fold(
    const void* __restrict__ Wi, const void* __restrict__ Wf,
    const void* __restrict__ Wo, const void* __restrict__ Wc,
    const void* __restrict__ bi, const void* __restrict__ bfg,
    const void* __restrict__ bo, const void* __restrict__ bcg,
    const void* __restrict__ Wfc, const void* __restrict__ bfc,
    const int* __restrict__ flags,
    bf16_t* __restrict__ U, bf16_t* __restrict__ Uz, float* __restrict__ bias2)
{
  const int f32 = flags[0];
  int n = blockIdx.x; int g = n & 3; int j = n >> 2;
  const void* Wg = (g==0)?Wi:(g==1)?Wf:(g==2)?Wo:Wc;
  const void* bg = (g==0)?bi:(g==1)?bfg:(g==2)?bo:bcg;
  const size_t wb = (size_t)j*1280;
  int k = threadIdx.x;
  float acc = 0.f;
  for (int d=0; d<256; ++d)
    acc += ldF(Wg, wb+512+d, f32) * ldF(Wfc, (size_t)d*256+k, f32);
  U[(size_t)n*512 + k]        = f2b(acc + ldF(Wg, wb+1024+k, f32));
  U[(size_t)n*512 + 256 + k]  = f2b(ldF(Wg, wb+768+k, f32));
  Uz[(size_t)n*512 + k]       = f2b(ldF(Wg, wb+k, f32));
  Uz[(size_t)n*512 + 256 + k] = f2b(ldF(Wg, wb+256+k, f32));
  __shared__ float red[256];
  red[k] = ldF(Wg, wb+512+k, f32) * ldF(bfc, k, f32);
  __syncthreads();
  for (int s=128; s>0; s>>=1){ if (k<s) red[k]+=red[k+s]; __syncthreads(); }
  if (k==0) bias2[n] = red[0] + ldF(bg, j, f32);
}

// ---------------- cluster tables / memory transposes ----------------
__global__ __launch_bounds__(256) void k_tables(
    const int* __restrict__ clusters, const void* __restrict__ memory,
    const int* __restrict__ flags,
    bf16_t* __restrict__ flatMb, bf16_t* __restrict__ memT,
    int* __restrict__ slotD_g, int* __restrict__ kpad_g, int* __restrict__ ofs_g)
{
  __shared__ int slot_tmp[256];
  __shared__ int cofd[256];
  __shared__ int ofs_s[8], kpad_s[8];
  const int f32 = flags[0];
  const int i64 = flags[1];
  int tid = threadIdx.x;
  if (tid==0){
    int cc[8]={0,0,0,0,0,0,0,0};
    for (int d=0; d<256; ++d){
      int cv = i64 ? clusters[2*d] : clusters[d];
      int c = (cv - 1) & 7;          // defensive clamp
      cofd[d]=c; slot_tmp[d]=cc[c]++;
    }
    int o=0;
    for (int c=0;c<8;++c){ int kp=((cc[c]+31)/32)*32; ofs_s[c]=o; kpad_s[c]=kp; o+=kp; }
  }
  __syncthreads();
  for (int i=tid;i<64*512;i+=256) flatMb[i]=f2b(0.f);
  if (tid<8){ kpad_g[tid]=kpad_s[tid]; ofs_g[tid]=ofs_s[tid]; }
  if (tid<256) slotD_g[tid] = ofs_s[cofd[tid]] + slot_tmp[tid];
  __syncthreads();
  for (int i=tid; i<256*64; i+=256){
    int d = i>>6, m = i&63;
    int c = cofd[d];
    int slot = ofs_s[c] + slot_tmp[d];
    flatMb[(size_t)m*512 + slot] = f2b(ldF(memory, ((size_t)(c*64+m))*256 + d, f32));
  }
  for (int i=tid; i<256*512; i+=256){
    int d = i>>9, cm = i&511;
    memT[(size_t)d*512 + cm] = f2b(ldF(memory, (size_t)cm*256 + d, f32));
  }
}

// ---------------- persistent recurrence: 8 blocks x 16 batch rows ----------------
__global__ __launch_bounds__(512) void k_main(
    const void* __restrict__ x, const int* __restrict__ flags,
    const bf16_t* __restrict__ WfcC, const bf16_t* __restrict__ bfcC,
    const bf16_t* __restrict__ lwC, const bf16_t* __restrict__ gwC,
    const float* __restrict__ gzC, const bf16_t* __restrict__ XmC,
    const bf16_t* __restrict__ U, const bf16_t* __restrict__ Uz,
    const float* __restrict__ bias2,
    const bf16_t* __restrict__ memT, const bf16_t* __restrict__ flatMb,
    const int* __restrict__ slotD_g, const int* __restrict__ kpad_g,
    const int* __restrict__ ofs_g,
    void* __restrict__ outv)
{
  __shared__ bf16_t hB[16][520];    // [h | gd]
  __shared__ bf16_t lspS[16][520];  // cluster-permuted local_stats (pads stay 0)
  __shared__ bf16_t tB[16][520];    // softmax*global_w, (c,m) indexed
  __shared__ bf16_t zS[16][520];    // [z | zp]
  __shared__ bf16_t xiB[16][256];
  __shared__ float lwS[3][256];
  __shared__ float gzS[4][256];
  __shared__ float b2S[1024];
  __shared__ int slotD[256];
  __shared__ int kpadS[8], ofsS[8];

  const int tid = threadIdx.x;
  const int w = tid>>6, l = tid&63, q = l>>4, cl = l&15;
  const int r0 = blockIdx.x*16;
  const int f32 = flags[0];

  for (int i=tid; i<16*520; i+=512){
    hB[i/520][i%520]   = f2b(0.f);
    lspS[i/520][i%520] = f2b(0.f);
  }
  if (tid<256){
    lwS[0][tid]=b2f(lwC[tid]);
    lwS[1][tid]=b2f(lwC[256+tid]);
    lwS[2][tid]=b2f(lwC[512+tid]);
    gzS[0][tid]=gzC[tid];     gzS[1][tid]=gzC[256+tid];
    gzS[2][tid]=gzC[512+tid]; gzS[3][tid]=gzC[768+tid];
    slotD[tid] = slotD_g[tid];
  }
  for (int i=tid;i<1024;i+=512) b2S[i]=bias2[i];
  if (tid<8){ kpadS[tid]=kpad_g[tid]; ofsS[tid]=ofs_g[tid]; }
  const float gw_c = b2f(gwC[w]);          // wave w owns cluster w
  const float bfc0 = b2f(bfcC[w*32 + cl]);
  const float bfc1 = b2f(bfcC[w*32 + 16 + cl]);
  float creg[8][4];
#pragma unroll
  for (int a=0;a<8;++a)
#pragma unroll
    for (int b2=0;b2<4;++b2) creg[a][b2]=0.f;
  __syncthreads();

  for (int t=0; t<=96; ++t){
    // -- phase 0: compute z/zp inline for rows r0..r0+15 at step t -> zS
    if (t<96){
      for (int i=tid; i<16*256; i+=512){
        int r = i>>8, d = i&255;
        size_t base = (size_t)(r0+r)*6*PLANE + (size_t)t*256 + d;
        float xt = ldF(x, base          , f32);
        float xl = ldF(x, base +   PLANE, f32);
        float mk = ldF(x, base + 2*PLANE, f32);
        float de = ldF(x, base + 3*PLANE, f32);
        float xlb= ldF(x, base + 4*PLANE, f32);
        float deb= ldF(x, base + 5*PLANE, f32);
        float mean = b2f(XmC[t*256+d]);
        float dz  = expf(-fmaxf(0.f, de *gzS[0][d] + gzS[1][d]));
        float dzp = expf(-fmaxf(0.f, deb*gzS[2][d] + gzS[3][d]));
        float z  = mk*xt + (1.f-mk)*(dz *xl  + (1.f-dz )*mean);
        float zp = mk*xt + (1.f-mk)*(dzp*xlb + (1.f-dzp)*mean);
        zS[r][d]     = f2b(z);
        zS[r][256+d] = f2b(zp);
      }
    }
    // -- phase 1: x_i = h @ Wfc^T + bfc ; also out[t-1]
    {
      f32x4 a0 = {0,0,0,0}, a1 = {0,0,0,0};
      const int n0 = w*32;
#pragma unroll
      for (int ks=0; ks<8; ++ks){
        bf16x8 af = ld_frag(&hB[cl][ks*32 + q*8]);
        bf16x8 b0 = ld_frag(&WfcC[(size_t)(n0+cl)*256 + ks*32 + q*8]);
        bf16x8 b1 = ld_frag(&WfcC[(size_t)(n0+16+cl)*256 + ks*32 + q*8]);
        a0 = mfma_bf16(af, b0, a0);
        a1 = mfma_bf16(af, b1, a1);
      }
#pragma unroll
      for (int rr=0; rr<4; ++rr){
        int row = q*4+rr;
        float v0 = a0[rr]+bfc0, v1 = a1[rr]+bfc1;
        bf16_t h0=f2b(v0), h1=f2b(v1);
        xiB[row][n0+cl]=h0; xiB[row][n0+16+cl]=h1;
        if (t>0){
          size_t ob = ((size_t)(r0+row)*96 + (t-1))*256;
          if (f32){
            ((float*)outv)[ob + n0 + cl]      = v0;
            ((float*)outv)[ob + n0 + 16 + cl] = v1;
          } else {
            ((bf16_t*)outv)[ob + n0 + cl]      = h0;
            ((bf16_t*)outv)[ob + n0 + 16 + cl] = h1;
          }
        }
      }
      __syncthreads();
    }
    if (t==96) break;
    // -- phase 2: ls = lw0*z + lw1*zp + lw2*x_i -> cluster-permuted slots
    for (int i=tid; i<16*256; i+=512){
      int r = i>>8, d = i&255;
      float ls = lwS[0][d]*b2f(zS[r][d]) + lwS[1][d]*b2f(zS[r][256+d])
               + lwS[2][d]*b2f(xiB[r][d]);
      lspS[r][slotD[d]] = f2b(ls);
    }
    __syncthreads();
    // -- phase 3: per-cluster scores + softmax -> tB
    {
      const int kp = kpadS[w], ko = ofsS[w];
      f32x4 sa[4];
#pragma unroll
      for (int nt=0;nt<4;++nt) sa[nt]=(f32x4){0,0,0,0};
      for (int ks=0; ks<(kp>>5); ++ks){
        bf16x8 af = ld_frag(&lspS[cl][ko + ks*32 + q*8]);
#pragma unroll
        for (int nt=0;nt<4;++nt){
          bf16x8 bv = ld_frag(&flatMb[(size_t)(nt*16+cl)*512 + ko + ks*32 + q*8]);
          sa[nt] = mfma_bf16(af, bv, sa[nt]);
        }
      }
#pragma unroll
      for (int rr=0; rr<4; ++rr){
        float mx = fmaxf(fmaxf(sa[0][rr],sa[1][rr]),fmaxf(sa[2][rr],sa[3][rr]));
        mx = fmaxf(mx, __shfl_xor(mx,1));
        mx = fmaxf(mx, __shfl_xor(mx,2));
        mx = fmaxf(mx, __shfl_xor(mx,4));
        mx = fmaxf(mx, __shfl_xor(mx,8));
        float e0=expf(sa[0][rr]-mx), e1=expf(sa[1][rr]-mx);
        float e2=expf(sa[2][rr]-mx), e3=expf(sa[3][rr]-mx);
        float s = e0+e1+e2+e3;
        s += __shfl_xor(s,1); s += __shfl_xor(s,2);
        s += __shfl_xor(s,4); s += __shfl_xor(s,8);
        float sc = gw_c / s;
        int row = q*4+rr;
        tB[row][w*64 +  0 + cl] = f2b(e0*sc);
        tB[row][w*64 + 16 + cl] = f2b(e1*sc);
        tB[row][w*64 + 32 + cl] = f2b(e2*sc);
        tB[row][w*64 + 48 + cl] = f2b(e3*sc);
      }
      __syncthreads();
    }
    // -- phase 4: gd = t @ memT -> hB[:,256:512]
    {
      f32x4 g0={0,0,0,0}, g1={0,0,0,0};
      const int n0 = w*32;
#pragma unroll
      for (int ks=0; ks<16; ++ks){
        bf16x8 af = ld_frag(&tB[cl][ks*32 + q*8]);
        bf16x8 b0 = ld_frag(&memT[(size_t)(n0+cl)*512 + ks*32 + q*8]);
        bf16x8 b1 = ld_frag(&memT[(size_t)(n0+16+cl)*512 + ks*32 + q*8]);
        g0 = mfma_bf16(af,b0,g0); g1 = mfma_bf16(af,b1,g1);
      }
#pragma unroll
      for (int rr=0;rr<4;++rr){
        int row=q*4+rr;
        hB[row][256 + n0 + cl]      = f2b(g0[rr]);
        hB[row][256 + n0 + 16 + cl] = f2b(g1[rr]);
      }
      __syncthreads();
    }
    // -- phase 5: gates = bias2 + zS@Uz^T + [h|gd]@U^T ; phase 6: LSTM update
    {
      f32x4 acc[8];
#pragma unroll
      for (int nt=0; nt<8; ++nt){
        float bv = b2S[w*128 + nt*16 + cl];
        acc[nt] = (f32x4){bv,bv,bv,bv};
      }
#pragma unroll
      for (int ks=0; ks<16; ++ks){
        bf16x8 az = ld_frag(&zS[cl][ks*32 + q*8]);
#pragma unroll
        for (int nt=0; nt<8; ++nt){
          bf16x8 bv = ld_frag(&Uz[(size_t)(w*128 + nt*16 + cl)*512 + ks*32 + q*8]);
          acc[nt] = mfma_bf16(az, bv, acc[nt]);
        }
      }
#pragma unroll
      for (int ks=0; ks<16; ++ks){
        bf16x8 ah = ld_frag(&hB[cl][ks*32 + q*8]);
#pragma unroll
        for (int nt=0; nt<8; ++nt){
          bf16x8 bv = ld_frag(&U[(size_t)(w*128 + nt*16 + cl)*512 + ks*32 + q*8]);
          acc[nt] = mfma_bf16(ah, bv, acc[nt]);
        }
      }
      __syncthreads();   // all hB/zS reads done before h writes
      const int base = l & ~3;
#pragma unroll
      for (int nt=0; nt<8; ++nt){
        int j = w*32 + nt*4 + (cl>>2);
#pragma unroll
        for (int rr=0; rr<4; ++rr){
          float p = acc[nt][rr];
          float pi = __shfl(p, base+0);
          float pf = __shfl(p, base+1);
          float po = __shfl(p, base+2);
          float pc = __shfl(p, base+3);
          float iv = 1.f/(1.f+expf(-pi));
          float fv = 1.f/(1.f+expf(-pf));
          float ov = 1.f/(1.f+expf(-po));
          float cv = tanhf(pc);
          float cn = fv*creg[nt][rr] + iv*cv;
          creg[nt][rr] = cn;
          float hv = ov * tanhf(cn);
          if ((l&3)==0) hB[q*4+rr][j] = f2b(hv);
        }
      }
      __syncthreads();
    }
  }
}

extern "C" void kernel_launch(void* const* d_in, const int* in_sizes, int n_in,
                              void* d_out, int out_size, void* d_ws, size_t ws_size,
                              hipStream_t stream)
{
  const void* x       = d_in[0];
  const void* Xmean   = d_in[1];
  const int*  clusters= (const int*)d_in[2];
  const void* Wi  = d_in[3];
  const void* bi  = d_in[4];
  const void* Wf  = d_in[5];
  const void* bfp = d_in[6];
  const void* Wo  = d_in[7];
  const void* bo  = d_in[8];
  const void* Wc  = d_in[9];
  const void* bcp = d_in[10];
  const void* Wfc = d_in[11];
  const void* bfc = d_in[12];
  const void* gzw = d_in[13];
  const void* gzb = d_in[14];
  const void* gzpw= d_in[15];
  const void* gzpb= d_in[16];
  const void* memory = d_in[17];
  const void* localw = d_in[18];
  const void* globalw= d_in[19];
  (void)in_sizes; (void)n_in; (void)out_size; (void)ws_size;

  char* ws = (char*)d_ws;
  size_t off = 0;
  auto take = [&](size_t bytes)->char*{
    char* p = ws + off; off = (off + bytes + 255) & ~(size_t)255; return p; };
  int*    flags  = (int*)   take(16);
  bf16_t* U      = (bf16_t*)take((size_t)1024*512*2);   // 1 MB
  bf16_t* Uz     = (bf16_t*)take((size_t)1024*512*2);   // 1 MB
  bf16_t* memT   = (bf16_t*)take((size_t)256*512*2);    // 256 KB
  bf16_t* flatMb = (bf16_t*)take((size_t)64*512*2);     // 64 KB
  bf16_t* WfcC   = (bf16_t*)take((size_t)65536*2);      // 128 KB
  bf16_t* XmC    = (bf16_t*)take((size_t)24576*2);      // 48 KB
  bf16_t* bfcC   = (bf16_t*)take(256*2);
  bf16_t* lwC    = (bf16_t*)take(768*2);
  bf16_t* gwC    = (bf16_t*)take(8*2);
  float*  gzC    = (float*) take(1024*4);
  float*  bias2  = (float*) take(1024*4);
  int* slotD = (int*)take(256*4);
  int* kpad  = (int*)take(8*4);
  int* ofsb  = (int*)take(8*4);
  // total ~2.6 MB

  k_detect<<<1,   64, 0,stream>>>((const uint32_t*)x, (const uint32_t*)clusters, flags);
  k_canon <<<256, 256,0,stream>>>(Wfc, Xmean, bfc, localw, globalw,
                                  gzw, gzb, gzpw, gzpb, flags,
                                  WfcC, XmC, bfcC, lwC, gwC, gzC);
  k_fold  <<<1024,256,0,stream>>>(Wi,Wf,Wo,Wc, bi,bfp,bo,bcp, Wfc,bfc, flags,
                                  U, Uz, bias2);
  k_tables<<<1,   256,0,stream>>>(clusters, memory, flags, flatMb, memT,
                                  slotD, kpad, ofsb);
  k_main  <<<8,   512,0,stream>>>(x, flags, WfcC, bfcC, lwC, gwC, gzC, XmC,
                                  U, Uz, bias2, memT, flatMb,
                                  slotD, kpad, ofsb, d_out);
}

// Round 5
// 5730.335 us; speedup vs baseline: 1.5232x; 1.5232x over previous
//
#include <hip/hip_runtime.h>
#include <hip/hip_bf16.h>
#include <hip/hip_fp16.h>
#include <cstdint>
#include <cstddef>

// B=128 T=96 D=256 H=256 C=8 M=64, COMB=1280
// combined = [z | zp | x_i | gd | h], gate interleave n=4j+g (g: i,f,o,c)
//   U [n][512]: k<256 -> W_h[j][k] + sum_d W_xi[j][d]*W_fc[d][k]; k>=256 -> W_gd
//   Uz[n][512]: W_g[j][0:512] (z|zp)
//   bias2[n]  : b_g[j] + sum_d W_xi[j][d]*b_fc[d]
// zc[t*128+b][n] (fp16) = bias2[n] + Zcat[t*128+b] @ Uz^T  (parallel precompute)
// Sequential k_main: 8 blocks x 16 rows x 1024 threads (16 waves, 4/SIMD).
// Inputs fp32-or-bf16 (clusters int64-or-int32) runtime-detected; out follows.

#define PLANE 24576   // 96*256

using bf16_t = __hip_bfloat16;
typedef __bf16 bf16x8 __attribute__((ext_vector_type(8)));
typedef float  f32x4  __attribute__((ext_vector_type(4)));

__device__ __forceinline__ float  b2f(bf16_t v){ return __bfloat162float(v); }
__device__ __forceinline__ bf16_t f2b(float v){ return __float2bfloat16(v); }
__device__ __forceinline__ float ldF(const void* p, size_t i, int f32){
  return f32 ? ((const float*)p)[i] : b2f(((const bf16_t*)p)[i]);
}
__device__ __forceinline__ bf16x8 ld_frag(const void* p){
  union { uint4 u; bf16x8 v; } c;
  c.u = *(const uint4*)p;
  return c.v;
}
__device__ __forceinline__ f32x4 mfma_bf16(bf16x8 a, bf16x8 b, f32x4 c){
  return __builtin_amdgcn_mfma_f32_16x16x32_bf16(a, b, c, 0, 0, 0);
}

// ---------------- dtype detection ----------------
__global__ __launch_bounds__(64) void k_detect(
    const uint32_t* __restrict__ xu, const uint32_t* __restrict__ clu,
    int* __restrict__ flags)
{
  __shared__ int cnt[2];
  int t = threadIdx.x;
  if (t < 2) cnt[t] = 0;
  __syncthreads();
  uint32_t v = xu[2*PLANE + t];                    // fp32 Mask plane probe
  if (v == 0u || v == 0x3F800000u) atomicAdd(&cnt[0], 1);
  if (clu[2*t + 1] == 0u) atomicAdd(&cnt[1], 1);   // int64 high-half probe
  __syncthreads();
  if (t == 0){
    flags[0] = (cnt[0] >= 48) ? 1 : 0;
    flags[1] = (cnt[1] >= 60) ? 1 : 0;
  }
}

// ---------------- canonicalize small tensors ----------------
__global__ __launch_bounds__(256) void k_canon(
    const void* __restrict__ Wfc, const void* __restrict__ Xmean,
    const void* __restrict__ bfc, const void* __restrict__ localw,
    const void* __restrict__ globalw, const void* __restrict__ gzw,
    const void* __restrict__ gzb, const void* __restrict__ gzpw,
    const void* __restrict__ gzpb, const int* __restrict__ flags,
    bf16_t* __restrict__ WfcC, bf16_t* __restrict__ XmC,
    bf16_t* __restrict__ bfcC, bf16_t* __restrict__ lwC,
    bf16_t* __restrict__ gwC, float* __restrict__ gzC)
{
  const int f32 = flags[0];
  int i = blockIdx.x*256 + threadIdx.x;
  if (i < 65536) WfcC[i] = f2b(ldF(Wfc, i, f32));
  if (i < 24576) XmC[i]  = f2b(ldF(Xmean, i, f32));
  if (i < 256)   bfcC[i] = f2b(ldF(bfc, i, f32));
  if (i < 768)   lwC[i]  = f2b(ldF(localw, i, f32));
  if (i < 8)     gwC[i]  = f2b(ldF(globalw, i, f32));
  if (i < 256){
    gzC[i]       = ldF(gzw,  i, f32);
    gzC[256 + i] = ldF(gzb,  i, f32);
    gzC[512 + i] = ldF(gzpw, i, f32);
    gzC[768 + i] = ldF(gzpb, i, f32);
  }
}

// ---------------- weight folding ----------------
__global__ __launch_bounds__(256) void k_fold(
    const void* __restrict__ Wi, const void* __restrict__ Wf,
    const void* __restrict__ Wo, const void* __restrict__ Wc,
    const void* __restrict__ bi, const void* __restrict__ bfg,
    const void* __restrict__ bo, const void* __restrict__ bcg,
    const void* __restrict__ Wfc, const void* __restrict__ bfc,
    const int* __restrict__ flags,
    bf16_t* __restrict__ U, bf16_t* __restrict__ Uz, float* __restrict__ bias2)
{
  const int f32 = flags[0];
  int n = blockIdx.x; int g = n & 3; int j = n >> 2;
  const void* Wg = (g==0)?Wi:(g==1)?Wf:(g==2)?Wo:Wc;
  const void* bg = (g==0)?bi:(g==1)?bfg:(g==2)?bo:bcg;
  const size_t wb = (size_t)j*1280;
  int k = threadIdx.x;
  float acc = 0.f;
  for (int d=0; d<256; ++d)
    acc += ldF(Wg, wb+512+d, f32) * ldF(Wfc, (size_t)d*256+k, f32);
  U[(size_t)n*512 + k]        = f2b(acc + ldF(Wg, wb+1024+k, f32));
  U[(size_t)n*512 + 256 + k]  = f2b(ldF(Wg, wb+768+k, f32));
  Uz[(size_t)n*512 + k]       = f2b(ldF(Wg, wb+k, f32));
  Uz[(size_t)n*512 + 256 + k] = f2b(ldF(Wg, wb+256+k, f32));
  __shared__ float red[256];
  red[k] = ldF(Wg, wb+512+k, f32) * ldF(bfc, k, f32);
  __syncthreads();
  for (int s=128; s>0; s>>=1){ if (k<s) red[k]+=red[k+s]; __syncthreads(); }
  if (k==0) bias2[n] = red[0] + ldF(bg, j, f32);
}

// ---------------- cluster tables / memory transposes ----------------
__global__ __launch_bounds__(256) void k_tables(
    const int* __restrict__ clusters, const void* __restrict__ memory,
    const int* __restrict__ flags,
    bf16_t* __restrict__ flatMb, bf16_t* __restrict__ memT,
    int* __restrict__ slotD_g, int* __restrict__ kpad_g, int* __restrict__ ofs_g)
{
  __shared__ int slot_tmp[256];
  __shared__ int cofd[256];
  __shared__ int ofs_s[8], kpad_s[8];
  const int f32 = flags[0];
  const int i64 = flags[1];
  int tid = threadIdx.x;
  if (tid==0){
    int cc[8]={0,0,0,0,0,0,0,0};
    for (int d=0; d<256; ++d){
      int cv = i64 ? clusters[2*d] : clusters[d];
      int c = (cv - 1) & 7;
      cofd[d]=c; slot_tmp[d]=cc[c]++;
    }
    int o=0;
    for (int c=0;c<8;++c){ int kp=((cc[c]+31)/32)*32; ofs_s[c]=o; kpad_s[c]=kp; o+=kp; }
  }
  __syncthreads();
  for (int i=tid;i<64*512;i+=256) flatMb[i]=f2b(0.f);
  if (tid<8){ kpad_g[tid]=kpad_s[tid]; ofs_g[tid]=ofs_s[tid]; }
  if (tid<256) slotD_g[tid] = ofs_s[cofd[tid]] + slot_tmp[tid];
  __syncthreads();
  for (int i=tid; i<256*64; i+=256){
    int d = i>>6, m = i&63;
    int c = cofd[d];
    int slot = ofs_s[c] + slot_tmp[d];
    flatMb[(size_t)m*512 + slot] = f2b(ldF(memory, ((size_t)(c*64+m))*256 + d, f32));
  }
  for (int i=tid; i<256*512; i+=256){
    int d = i>>9, cm = i&511;
    memT[(size_t)d*512 + cm] = f2b(ldF(memory, (size_t)cm*256 + d, f32));
  }
}

// ---------------- z / zp -> Zcat, t-major rows (t*128+b) ----------------
__global__ __launch_bounds__(256) void k_zzp(
    const void* __restrict__ x, const bf16_t* __restrict__ XmC,
    const float* __restrict__ gzC, const int* __restrict__ flags,
    bf16_t* __restrict__ Zcat)
{
  const int f32 = flags[0];
  int r = blockIdx.x;             // r = t*128 + b
  int t = r >> 7, b = r & 127, d = threadIdx.x;
  size_t base = (size_t)b*6*PLANE + (size_t)t*256 + d;
  float xt = ldF(x, base          , f32);
  float xl = ldF(x, base +   PLANE, f32);
  float mk = ldF(x, base + 2*PLANE, f32);
  float de = ldF(x, base + 3*PLANE, f32);
  float xlb= ldF(x, base + 4*PLANE, f32);
  float deb= ldF(x, base + 5*PLANE, f32);
  float mean = b2f(XmC[t*256+d]);
  float dz  = expf(-fmaxf(0.f, de *gzC[d]     + gzC[256+d]));
  float dzp = expf(-fmaxf(0.f, deb*gzC[512+d] + gzC[768+d]));
  float z  = mk*xt + (1.f-mk)*(dz *xl  + (1.f-dz )*mean);
  float zp = mk*xt + (1.f-mk)*(dzp*xlb + (1.f-dzp)*mean);
  Zcat[(size_t)r*512 + d]       = f2b(z);
  Zcat[(size_t)r*512 + 256 + d] = f2b(zp);
}

// ---------------- zc GEMM: zc[m][n] = bias2[n] + Zcat[m] @ Uz^T (fp16 out) ---
__global__ __launch_bounds__(256) void k_zc(
    const bf16_t* __restrict__ Zcat, const bf16_t* __restrict__ Uz,
    const float* __restrict__ bias2, __half* __restrict__ zc)
{
  const int tid = threadIdx.x;
  const int w = tid>>6, l = tid&63, q=l>>4, cl=l&15;
  const int mq = w&1, nq = w>>1;
  const int m0 = blockIdx.x*128, n0 = blockIdx.y*128;
  f32x4 acc[4][4];
#pragma unroll
  for (int a=0;a<4;++a)
#pragma unroll
    for (int b2=0;b2<4;++b2) acc[a][b2] = (f32x4){0.f,0.f,0.f,0.f};
  for (int ks=0; ks<16; ++ks){
    bf16x8 av[4], bv[4];
#pragma unroll
    for (int mi=0;mi<4;++mi)
      av[mi] = ld_frag(&Zcat[(size_t)(m0+mq*64+mi*16+cl)*512 + ks*32 + q*8]);
#pragma unroll
    for (int ni=0;ni<4;++ni)
      bv[ni] = ld_frag(&Uz[(size_t)(n0+nq*64+ni*16+cl)*512 + ks*32 + q*8]);
#pragma unroll
    for (int mi=0;mi<4;++mi)
#pragma unroll
      for (int ni=0;ni<4;++ni)
        acc[mi][ni] = mfma_bf16(av[mi], bv[ni], acc[mi][ni]);
  }
#pragma unroll
  for (int mi=0;mi<4;++mi)
#pragma unroll
    for (int ni=0;ni<4;++ni)
#pragma unroll
      for (int rr=0;rr<4;++rr){
        int m = m0 + mq*64 + mi*16 + q*4 + rr;
        int n = n0 + nq*64 + ni*16 + cl;
        zc[(size_t)m*1024 + n] = __float2half(acc[mi][ni][rr] + bias2[n]);
      }
}

// ---------------- persistent recurrence: 8 blocks x 16 rows x 16 waves -------
template<int USE_ZC>
__global__ __launch_bounds__(1024) void k_main(
    const int* __restrict__ flags,
    const bf16_t* __restrict__ WfcC, const bf16_t* __restrict__ bfcC,
    const bf16_t* __restrict__ lwC, const bf16_t* __restrict__ gwC,
    const bf16_t* __restrict__ Zcat, const __half* __restrict__ zc,
    const bf16_t* __restrict__ U, const bf16_t* __restrict__ Uz,
    const float* __restrict__ bias2,
    const bf16_t* __restrict__ memT, const bf16_t* __restrict__ flatMb,
    const int* __restrict__ slotD_g, const int* __restrict__ kpad_g,
    const int* __restrict__ ofs_g,
    void* __restrict__ outv)
{
  __shared__ bf16_t hB[16][520];    // [h | gd]
  __shared__ bf16_t lspS[16][520];  // cluster-permuted local_stats (pads stay 0)
  __shared__ bf16_t tB[16][520];    // softmax*global_w, (c,m) indexed
  __shared__ bf16_t zS[16][520];    // [z | zp]
  __shared__ bf16_t xiB[16][256];
  __shared__ float lwS[3][256];
  __shared__ float b2S[1024];
  __shared__ int slotD[256];
  __shared__ int kpadS[8], ofsS[8];

  const int tid = threadIdx.x;
  const int W = tid>>6, l = tid&63, q = l>>4, cl = l&15;
  const int r0 = blockIdx.x*16;
  const int f32 = flags[0];

  for (int i=tid; i<16*520; i+=1024){
    hB[i/520][i%520]   = f2b(0.f);
    lspS[i/520][i%520] = f2b(0.f);
  }
  if (tid<256){
    lwS[0][tid]=b2f(lwC[tid]);
    lwS[1][tid]=b2f(lwC[256+tid]);
    lwS[2][tid]=b2f(lwC[512+tid]);
    slotD[tid] = slotD_g[tid];
  }
  if (tid<1024 && !USE_ZC) b2S[tid]=bias2[tid];
  if (tid<8){ kpadS[tid]=kpad_g[tid]; ofsS[tid]=ofs_g[tid]; }
  const float gw_c = (W<8) ? b2f(gwC[W]) : 0.f;   // waves 0-7 own clusters
  const int n1 = W*16;                             // phase-1/4 col slice
  const float bfc0 = b2f(bfcC[n1 + cl]);
  float creg[4][4];
#pragma unroll
  for (int a=0;a<4;++a)
#pragma unroll
    for (int b2=0;b2<4;++b2) creg[a][b2]=0.f;
  __syncthreads();

  for (int t=0; t<=96; ++t){
    // -- phase 0: stage zS rows (t*128 + r0 .. +15) -- one shot, 1024 threads
    if (t<96){
      int r = tid>>6, c8 = (tid&63)*8;
      uint4 v = *(const uint4*)(Zcat + ((size_t)(t*128) + r0 + r)*512 + c8);
      *(uint4*)(&zS[r][c8]) = v;
    }
    // -- phase 1: x_i = h @ Wfc^T + bfc ; out[t-1]. wave W -> cols n1..n1+15
    {
      f32x4 a0 = {0,0,0,0};
#pragma unroll
      for (int ks=0; ks<8; ++ks){
        bf16x8 af = ld_frag(&hB[cl][ks*32 + q*8]);
        bf16x8 b0 = ld_frag(&WfcC[(size_t)(n1+cl)*256 + ks*32 + q*8]);
        a0 = mfma_bf16(af, b0, a0);
      }
#pragma unroll
      for (int rr=0; rr<4; ++rr){
        int row = q*4+rr;
        float v0 = a0[rr]+bfc0;
        bf16_t h0=f2b(v0);
        xiB[row][n1+cl]=h0;
        if (t>0){
          size_t ob = ((size_t)(r0+row)*96 + (t-1))*256;
          if (f32) ((float*)outv)[ob + n1 + cl] = v0;
          else     ((bf16_t*)outv)[ob + n1 + cl] = h0;
        }
      }
      __syncthreads();
    }
    if (t==96) break;
    // -- phase 2: ls -> cluster-permuted slots
    for (int i=tid; i<16*256; i+=1024){
      int r = i>>8, d = i&255;
      float ls = lwS[0][d]*b2f(zS[r][d]) + lwS[1][d]*b2f(zS[r][256+d])
               + lwS[2][d]*b2f(xiB[r][d]);
      lspS[r][slotD[d]] = f2b(ls);
    }
    __syncthreads();
    // -- phase 3: per-cluster scores + softmax -> tB (waves 0-7 only)
    if (W < 8){
      const int kp = kpadS[W], ko = ofsS[W];
      f32x4 sa[4];
#pragma unroll
      for (int nt=0;nt<4;++nt) sa[nt]=(f32x4){0,0,0,0};
      for (int ks=0; ks<(kp>>5); ++ks){
        bf16x8 af = ld_frag(&lspS[cl][ko + ks*32 + q*8]);
#pragma unroll
        for (int nt=0;nt<4;++nt){
          bf16x8 bv = ld_frag(&flatMb[(size_t)(nt*16+cl)*512 + ko + ks*32 + q*8]);
          sa[nt] = mfma_bf16(af, bv, sa[nt]);
        }
      }
#pragma unroll
      for (int rr=0; rr<4; ++rr){
        float mx = fmaxf(fmaxf(sa[0][rr],sa[1][rr]),fmaxf(sa[2][rr],sa[3][rr]));
        mx = fmaxf(mx, __shfl_xor(mx,1));
        mx = fmaxf(mx, __shfl_xor(mx,2));
        mx = fmaxf(mx, __shfl_xor(mx,4));
        mx = fmaxf(mx, __shfl_xor(mx,8));
        float e0=expf(sa[0][rr]-mx), e1=expf(sa[1][rr]-mx);
        float e2=expf(sa[2][rr]-mx), e3=expf(sa[3][rr]-mx);
        float s = e0+e1+e2+e3;
        s += __shfl_xor(s,1); s += __shfl_xor(s,2);
        s += __shfl_xor(s,4); s += __shfl_xor(s,8);
        float sc = gw_c / s;
        int row = q*4+rr;
        tB[row][W*64 +  0 + cl] = f2b(e0*sc);
        tB[row][W*64 + 16 + cl] = f2b(e1*sc);
        tB[row][W*64 + 32 + cl] = f2b(e2*sc);
        tB[row][W*64 + 48 + cl] = f2b(e3*sc);
      }
    }
    __syncthreads();
    // -- phase 4: gd = t @ memT -> hB[:,256:512]. wave W -> cols n1..n1+15
    {
      f32x4 g0={0,0,0,0};
#pragma unroll
      for (int ks=0; ks<16; ++ks){
        bf16x8 af = ld_frag(&tB[cl][ks*32 + q*8]);
        bf16x8 b0 = ld_frag(&memT[(size_t)(n1+cl)*512 + ks*32 + q*8]);
        g0 = mfma_bf16(af,b0,g0);
      }
#pragma unroll
      for (int rr=0;rr<4;++rr)
        hB[q*4+rr][256 + n1 + cl] = f2b(g0[rr]);
      __syncthreads();
    }
    // -- phase 5: gates = zc + [h|gd]@U^T. wave W -> gate cols W*64..W*64+63
    {
      f32x4 acc[4];
      if (USE_ZC){
#pragma unroll
        for (int nt=0; nt<4; ++nt)
#pragma unroll
          for (int rr=0; rr<4; ++rr)
            acc[nt][rr] = __half2float(
              zc[((size_t)(t*128) + r0 + q*4+rr)*1024 + W*64 + nt*16 + cl]);
      } else {
#pragma unroll
        for (int nt=0; nt<4; ++nt){
          float bv = b2S[W*64 + nt*16 + cl];
          acc[nt] = (f32x4){bv,bv,bv,bv};
        }
#pragma unroll
        for (int ks=0; ks<16; ++ks){
          bf16x8 az = ld_frag(&zS[cl][ks*32 + q*8]);
#pragma unroll
          for (int nt=0; nt<4; ++nt){
            bf16x8 bv = ld_frag(&Uz[(size_t)(W*64 + nt*16 + cl)*512 + ks*32 + q*8]);
            acc[nt] = mfma_bf16(az, bv, acc[nt]);
          }
        }
      }
#pragma unroll
      for (int ks=0; ks<16; ++ks){
        bf16x8 ah = ld_frag(&hB[cl][ks*32 + q*8]);
#pragma unroll
        for (int nt=0; nt<4; ++nt){
          bf16x8 bv = ld_frag(&U[(size_t)(W*64 + nt*16 + cl)*512 + ks*32 + q*8]);
          acc[nt] = mfma_bf16(ah, bv, acc[nt]);
        }
      }
      __syncthreads();   // all hB/zS reads done before h writes
      const int base = l & ~3;
#pragma unroll
      for (int nt=0; nt<4; ++nt){
        int j = W*16 + nt*4 + (cl>>2);
#pragma unroll
        for (int rr=0; rr<4; ++rr){
          float p = acc[nt][rr];
          float pi = __shfl(p, base+0);
          float pf = __shfl(p, base+1);
          float po = __shfl(p, base+2);
          float pc = __shfl(p, base+3);
          float iv = 1.f/(1.f+expf(-pi));
          float fv = 1.f/(1.f+expf(-pf));
          float ov = 1.f/(1.f+expf(-po));
          float cv = tanhf(pc);
          float cn = fv*creg[nt][rr] + iv*cv;
          creg[nt][rr] = cn;
          float hv = ov * tanhf(cn);
          if ((l&3)==0) hB[q*4+rr][j] = f2b(hv);
        }
      }
      __syncthreads();
    }
  }
}

extern "C" void kernel_launch(void* const* d_in, const int* in_sizes, int n_in,
                              void* d_out, int out_size, void* d_ws, size_t ws_size,
                              hipStream_t stream)
{
  const void* x       = d_in[0];
  const void* Xmean   = d_in[1];
  const int*  clusters= (const int*)d_in[2];
  const void* Wi  = d_in[3];
  const void* bi  = d_in[4];
  const void* Wf  = d_in[5];
  const void* bfp = d_in[6];
  const void* Wo  = d_in[7];
  const void* bo  = d_in[8];
  const void* Wc  = d_in[9];
  const void* bcp = d_in[10];
  const void* Wfc = d_in[11];
  const void* bfc = d_in[12];
  const void* gzw = d_in[13];
  const void* gzb = d_in[14];
  const void* gzpw= d_in[15];
  const void* gzpb= d_in[16];
  const void* memory = d_in[17];
  const void* localw = d_in[18];
  const void* globalw= d_in[19];
  (void)in_sizes; (void)n_in; (void)out_size;

  char* ws = (char*)d_ws;
  size_t off = 0;
  auto take = [&](size_t bytes)->char*{
    char* p = ws + off; off = (off + bytes + 255) & ~(size_t)255; return p; };
  int*    flags  = (int*)   take(16);
  bf16_t* U      = (bf16_t*)take((size_t)1024*512*2);     // 1 MB
  bf16_t* Uz     = (bf16_t*)take((size_t)1024*512*2);     // 1 MB
  bf16_t* memT   = (bf16_t*)take((size_t)256*512*2);      // 256 KB
  bf16_t* flatMb = (bf16_t*)take((size_t)64*512*2);       // 64 KB
  bf16_t* WfcC   = (bf16_t*)take((size_t)65536*2);        // 128 KB
  bf16_t* XmC    = (bf16_t*)take((size_t)24576*2);        // 48 KB
  bf16_t* bfcC   = (bf16_t*)take(256*2);
  bf16_t* lwC    = (bf16_t*)take(768*2);
  bf16_t* gwC    = (bf16_t*)take(8*2);
  float*  gzC    = (float*) take(1024*4);
  float*  bias2  = (float*) take(1024*4);
  int* slotD = (int*)take(256*4);
  int* kpad  = (int*)take(8*4);
  int* ofsb  = (int*)take(8*4);
  bf16_t* Zcat   = (bf16_t*)take((size_t)12288*512*2);    // 12.6 MB
  size_t base_need = off;
  __half* zc     = (__half*)take((size_t)12288*1024*2);   // 25.2 MB
  const bool use_zc = (ws_size >= off);
  (void)base_need;

  k_detect<<<1,    64, 0,stream>>>((const uint32_t*)x, (const uint32_t*)clusters, flags);
  k_canon <<<256,  256,0,stream>>>(Wfc, Xmean, bfc, localw, globalw,
                                   gzw, gzb, gzpw, gzpb, flags,
                                   WfcC, XmC, bfcC, lwC, gwC, gzC);
  k_fold  <<<1024, 256,0,stream>>>(Wi,Wf,Wo,Wc, bi,bfp,bo,bcp, Wfc,bfc, flags,
                                   U, Uz, bias2);
  k_tables<<<1,    256,0,stream>>>(clusters, memory, flags, flatMb, memT,
                                   slotD, kpad, ofsb);
  k_zzp   <<<12288,256,0,stream>>>(x, XmC, gzC, flags, Zcat);
  if (use_zc){
    k_zc  <<<dim3(96,8),256,0,stream>>>(Zcat, Uz, bias2, zc);
    k_main<1><<<8, 1024,0,stream>>>(flags, WfcC, bfcC, lwC, gwC, Zcat, zc,
                                    U, Uz, bias2, memT, flatMb,
                                    slotD, kpad, ofsb, d_out);
  } else {
    k_main<0><<<8, 1024,0,stream>>>(flags, WfcC, bfcC, lwC, gwC, Zcat, zc,
                                    U, Uz, bias2, memT, flatMb,
                                    slotD, kpad, ofsb, d_out);
  }
}

// Round 6
// 2702.406 us; speedup vs baseline: 3.2299x; 2.1205x over previous
//
#include <hip/hip_runtime.h>
#include <hip/hip_bf16.h>
#include <hip/hip_fp16.h>
#include <cstdint>
#include <cstddef>

// B=128 T=96 D=256 H=256 C=8 M=64, COMB=1280
// gates = zc + h @ Uh^T + t @ G^T   (gate interleave n=4j+g)
//   Uh[n][256] = W_h[j] + W_xi[j]@Wfc      (k_fold, h-part of U)
//   G [n][512] = sum_d W_gd[n][d]*mem[cm][d]  (k_foldG; folds memT away)
//   zc[t*128+b][n] = bias2[n] + [z|zp] @ Uz^T  (fp16, k_zc)
// k_main: 128 blocks = 8 batch-groups(16 rows) x 16 N-slices(64 gate cols),
// weights LDS-resident for all 96 steps; 3 group-local global barriers/step.

#define PLANE 24576   // 96*256
#define GRP 16        // s-slices per group

using bf16_t = __hip_bfloat16;
typedef __bf16 bf16x8 __attribute__((ext_vector_type(8)));
typedef float  f32x4  __attribute__((ext_vector_type(4)));

__device__ __forceinline__ float  b2f(bf16_t v){ return __bfloat162float(v); }
__device__ __forceinline__ bf16_t f2b(float v){ return __float2bfloat16(v); }
__device__ __forceinline__ float ldF(const void* p, size_t i, int f32){
  return f32 ? ((const float*)p)[i] : b2f(((const bf16_t*)p)[i]);
}
__device__ __forceinline__ bf16x8 ld_frag(const void* p){
  union { uint4 u; bf16x8 v; } c;
  c.u = *(const uint4*)p;
  return c.v;
}
__device__ __forceinline__ f32x4 mfma_bf16(bf16x8 a, bf16x8 b, f32x4 c){
  return __builtin_amdgcn_mfma_f32_16x16x32_bf16(a, b, c, 0, 0, 0);
}

// group barrier: monotonic counter, device-scope
__device__ __forceinline__ void gbar(int* ctr, int target){
  __syncthreads();
  if (threadIdx.x == 0){
    __threadfence();
    atomicAdd(ctr, 1);
    while (atomicAdd(ctr, 0) < target) __builtin_amdgcn_s_sleep(2);
    __threadfence();
  }
  __syncthreads();
}

// ---------------- dtype detection ----------------
__global__ __launch_bounds__(64) void k_detect(
    const uint32_t* __restrict__ xu, const uint32_t* __restrict__ clu,
    int* __restrict__ flags)
{
  __shared__ int cnt[2];
  int t = threadIdx.x;
  if (t < 2) cnt[t] = 0;
  __syncthreads();
  uint32_t v = xu[2*PLANE + t];
  if (v == 0u || v == 0x3F800000u) atomicAdd(&cnt[0], 1);
  if (clu[2*t + 1] == 0u) atomicAdd(&cnt[1], 1);
  __syncthreads();
  if (t == 0){
    flags[0] = (cnt[0] >= 48) ? 1 : 0;
    flags[1] = (cnt[1] >= 60) ? 1 : 0;
  }
}

__global__ __launch_bounds__(64) void k_zero(int* __restrict__ bar){
  bar[threadIdx.x] = 0;
}

// ---------------- canonicalize small tensors ----------------
__global__ __launch_bounds__(256) void k_canon(
    const void* __restrict__ Wfc, const void* __restrict__ Xmean,
    const void* __restrict__ bfc, const void* __restrict__ localw,
    const void* __restrict__ globalw, const void* __restrict__ gzw,
    const void* __restrict__ gzb, const void* __restrict__ gzpw,
    const void* __restrict__ gzpb, const int* __restrict__ flags,
    bf16_t* __restrict__ WfcC, bf16_t* __restrict__ XmC,
    bf16_t* __restrict__ bfcC, bf16_t* __restrict__ lwC,
    bf16_t* __restrict__ gwC, float* __restrict__ gzC)
{
  const int f32 = flags[0];
  int i = blockIdx.x*256 + threadIdx.x;
  if (i < 65536) WfcC[i] = f2b(ldF(Wfc, i, f32));
  if (i < 24576) XmC[i]  = f2b(ldF(Xmean, i, f32));
  if (i < 256)   bfcC[i] = f2b(ldF(bfc, i, f32));
  if (i < 768)   lwC[i]  = f2b(ldF(localw, i, f32));
  if (i < 8)     gwC[i]  = f2b(ldF(globalw, i, f32));
  if (i < 256){
    gzC[i]       = ldF(gzw,  i, f32);
    gzC[256 + i] = ldF(gzb,  i, f32);
    gzC[512 + i] = ldF(gzpw, i, f32);
    gzC[768 + i] = ldF(gzpb, i, f32);
  }
}

// ---------------- weight folding: U(h-part folded), Uz, bias2 ----------------
__global__ __launch_bounds__(256) void k_fold(
    const void* __restrict__ Wi, const void* __restrict__ Wf,
    const void* __restrict__ Wo, const void* __restrict__ Wc,
    const void* __restrict__ bi, const void* __restrict__ bfg,
    const void* __restrict__ bo, const void* __restrict__ bcg,
    const void* __restrict__ Wfc, const void* __restrict__ bfc,
    const int* __restrict__ flags,
    bf16_t* __restrict__ U, bf16_t* __restrict__ Uz, float* __restrict__ bias2)
{
  const int f32 = flags[0];
  int n = blockIdx.x; int g = n & 3; int j = n >> 2;
  const void* Wg = (g==0)?Wi:(g==1)?Wf:(g==2)?Wo:Wc;
  const void* bg = (g==0)?bi:(g==1)?bfg:(g==2)?bo:bcg;
  const size_t wb = (size_t)j*1280;
  int k = threadIdx.x;
  float acc = 0.f;
  for (int d=0; d<256; ++d)
    acc += ldF(Wg, wb+512+d, f32) * ldF(Wfc, (size_t)d*256+k, f32);
  U[(size_t)n*512 + k]        = f2b(acc + ldF(Wg, wb+1024+k, f32));
  U[(size_t)n*512 + 256 + k]  = f2b(ldF(Wg, wb+768+k, f32));   // unused by k_main now
  Uz[(size_t)n*512 + k]       = f2b(ldF(Wg, wb+k, f32));
  Uz[(size_t)n*512 + 256 + k] = f2b(ldF(Wg, wb+256+k, f32));
  __shared__ float red[256];
  red[k] = ldF(Wg, wb+512+k, f32) * ldF(bfc, k, f32);
  __syncthreads();
  for (int s=128; s>0; s>>=1){ if (k<s) red[k]+=red[k+s]; __syncthreads(); }
  if (k==0) bias2[n] = red[0] + ldF(bg, j, f32);
}

// ---------------- G[n][cm] = sum_d W_gd[n][d] * mem[cm][d] ----------------
__global__ __launch_bounds__(256) void k_foldG(
    const void* __restrict__ Wi, const void* __restrict__ Wf,
    const void* __restrict__ Wo, const void* __restrict__ Wc,
    const void* __restrict__ memory, const int* __restrict__ flags,
    bf16_t* __restrict__ G)
{
  const int f32 = flags[0];
  __shared__ float wrow[4][256];
  int j = blockIdx.x; int tid = threadIdx.x;
  const void* Wg[4] = {Wi,Wf,Wo,Wc};
  for (int g=0; g<4; ++g)
    wrow[g][tid] = ldF(Wg[g], (size_t)j*1280 + 768 + tid, f32);
  __syncthreads();
  for (int half=0; half<2; ++half){
    int cm = half*256 + tid;
    float a0=0,a1=0,a2=0,a3=0;
    for (int d=0; d<256; ++d){
      float mv = ldF(memory, (size_t)cm*256 + d, f32);
      a0 += wrow[0][d]*mv; a1 += wrow[1][d]*mv;
      a2 += wrow[2][d]*mv; a3 += wrow[3][d]*mv;
    }
    G[(size_t)(4*j+0)*512 + cm] = f2b(a0);
    G[(size_t)(4*j+1)*512 + cm] = f2b(a1);
    G[(size_t)(4*j+2)*512 + cm] = f2b(a2);
    G[(size_t)(4*j+3)*512 + cm] = f2b(a3);
  }
}

// ---------------- cluster tables ----------------
__global__ __launch_bounds__(256) void k_tables(
    const int* __restrict__ clusters, const void* __restrict__ memory,
    const int* __restrict__ flags,
    bf16_t* __restrict__ flatMb,
    int* __restrict__ slotD_g, int* __restrict__ kpad_g, int* __restrict__ ofs_g)
{
  __shared__ int slot_tmp[256];
  __shared__ int cofd[256];
  __shared__ int ofs_s[8], kpad_s[8];
  const int f32 = flags[0];
  const int i64 = flags[1];
  int tid = threadIdx.x;
  if (tid==0){
    int cc[8]={0,0,0,0,0,0,0,0};
    for (int d=0; d<256; ++d){
      int cv = i64 ? clusters[2*d] : clusters[d];
      int c = (cv - 1) & 7;
      cofd[d]=c; slot_tmp[d]=cc[c]++;
    }
    int o=0;
    for (int c=0;c<8;++c){ int kp=((cc[c]+31)/32)*32; if (kp>96) kp=96;
      ofs_s[c]=o; kpad_s[c]=kp; o+=kp; }
  }
  __syncthreads();
  for (int i=tid;i<64*512;i+=256) flatMb[i]=f2b(0.f);
  if (tid<8){ kpad_g[tid]=kpad_s[tid]; ofs_g[tid]=ofs_s[tid]; }
  if (tid<256) slotD_g[tid] = ofs_s[cofd[tid]] + slot_tmp[tid];
  __syncthreads();
  for (int i=tid; i<256*64; i+=256){
    int d = i>>6, m = i&63;
    int c = cofd[d];
    int slot = slot_tmp[d];
    if (slot < kpad_s[c])
      flatMb[(size_t)m*512 + ofs_s[c] + slot] =
        f2b(ldF(memory, ((size_t)(c*64+m))*256 + d, f32));
  }
}

// ---------------- z / zp -> Zcat, t-major rows (t*128+b) ----------------
__global__ __launch_bounds__(256) void k_zzp(
    const void* __restrict__ x, const bf16_t* __restrict__ XmC,
    const float* __restrict__ gzC, const int* __restrict__ flags,
    bf16_t* __restrict__ Zcat)
{
  const int f32 = flags[0];
  int r = blockIdx.x;             // r = t*128 + b
  int t = r >> 7, b = r & 127, d = threadIdx.x;
  size_t base = (size_t)b*6*PLANE + (size_t)t*256 + d;
  float xt = ldF(x, base          , f32);
  float xl = ldF(x, base +   PLANE, f32);
  float mk = ldF(x, base + 2*PLANE, f32);
  float de = ldF(x, base + 3*PLANE, f32);
  float xlb= ldF(x, base + 4*PLANE, f32);
  float deb= ldF(x, base + 5*PLANE, f32);
  float mean = b2f(XmC[t*256+d]);
  float dz  = expf(-fmaxf(0.f, de *gzC[d]     + gzC[256+d]));
  float dzp = expf(-fmaxf(0.f, deb*gzC[512+d] + gzC[768+d]));
  float z  = mk*xt + (1.f-mk)*(dz *xl  + (1.f-dz )*mean);
  float zp = mk*xt + (1.f-mk)*(dzp*xlb + (1.f-dzp)*mean);
  Zcat[(size_t)r*512 + d]       = f2b(z);
  Zcat[(size_t)r*512 + 256 + d] = f2b(zp);
}

// ---------------- zc GEMM: zc[m][n] = bias2[n] + Zcat[m] @ Uz^T (fp16) ------
__global__ __launch_bounds__(256) void k_zc(
    const bf16_t* __restrict__ Zcat, const bf16_t* __restrict__ Uz,
    const float* __restrict__ bias2, __half* __restrict__ zc)
{
  const int tid = threadIdx.x;
  const int w = tid>>6, l = tid&63, q=l>>4, cl=l&15;
  const int mq = w&1, nq = w>>1;
  const int m0 = blockIdx.x*128, n0 = blockIdx.y*128;
  f32x4 acc[4][4];
#pragma unroll
  for (int a=0;a<4;++a)
#pragma unroll
    for (int b2=0;b2<4;++b2) acc[a][b2] = (f32x4){0.f,0.f,0.f,0.f};
  for (int ks=0; ks<16; ++ks){
    bf16x8 av[4], bv[4];
#pragma unroll
    for (int mi=0;mi<4;++mi)
      av[mi] = ld_frag(&Zcat[(size_t)(m0+mq*64+mi*16+cl)*512 + ks*32 + q*8]);
#pragma unroll
    for (int ni=0;ni<4;++ni)
      bv[ni] = ld_frag(&Uz[(size_t)(n0+nq*64+ni*16+cl)*512 + ks*32 + q*8]);
#pragma unroll
    for (int mi=0;mi<4;++mi)
#pragma unroll
      for (int ni=0;ni<4;++ni)
        acc[mi][ni] = mfma_bf16(av[mi], bv[ni], acc[mi][ni]);
  }
#pragma unroll
  for (int mi=0;mi<4;++mi)
#pragma unroll
    for (int ni=0;ni<4;++ni)
#pragma unroll
      for (int rr=0;rr<4;++rr){
        int m = m0 + mq*64 + mi*16 + q*4 + rr;
        int n = n0 + nq*64 + ni*16 + cl;
        zc[(size_t)m*1024 + n] = __float2half(acc[mi][ni][rr] + bias2[n]);
      }
}

// ---------------- k_main: 128 blocks (8 groups x 16 slices) x 256 thr -------
__global__ __launch_bounds__(256) void k_main(
    const int* __restrict__ flags,
    const bf16_t* __restrict__ WfcC, const bf16_t* __restrict__ bfcC,
    const bf16_t* __restrict__ lwC, const bf16_t* __restrict__ gwC,
    const bf16_t* __restrict__ U, const bf16_t* __restrict__ G,
    const __half* __restrict__ zc, const bf16_t* __restrict__ Zcat,
    const bf16_t* __restrict__ flatMb,
    const int* __restrict__ slotD_g, const int* __restrict__ kpad_g,
    const int* __restrict__ ofs_g,
    bf16_t* __restrict__ hX, bf16_t* __restrict__ xiX, bf16_t* __restrict__ tX,
    int* __restrict__ bar, void* __restrict__ outv)
{
  __shared__ bf16_t Us[64][264];    // Uh slice rows n0..n0+63
  __shared__ bf16_t Gs[64][520];    // G  slice
  __shared__ bf16_t hS[16][264];
  __shared__ bf16_t tS[16][520];
  __shared__ bf16_t WfcS[16][264];  // x_i cols s*16..
  __shared__ bf16_t fMb[64][104];   // own cluster's memory slots
  __shared__ bf16_t lsp[16][104];
  __shared__ float lwS[3][256];
  __shared__ float bfcS[16];
  __shared__ int slotD[256];
  __shared__ int clKO[2];           // [kpad, ofs] of own cluster

  const int tid = threadIdx.x;
  const int W = tid>>6, l = tid&63, q = l>>4, cl = l&15;
  const int g = blockIdx.x & 7, s = blockIdx.x >> 3;  // group g -> XCD g (swizzle)
  const int r0 = g*16;
  const int n0 = s*64;
  const int f32 = flags[0];
  int* barp = bar + g*4;

  // one-time staging (LDS-resident weights)
  for (int i=tid; i<64*32; i+=256){ int r=i>>5, c8=(i&31)*8;
    *(uint4*)(&Us[r][c8]) = *(const uint4*)(U + (size_t)(n0+r)*512 + c8); }
  for (int i=tid; i<64*64; i+=256){ int r=i>>6, c8=(i&63)*8;
    *(uint4*)(&Gs[r][c8]) = *(const uint4*)(G + (size_t)(n0+r)*512 + c8); }
  for (int i=tid; i<16*32; i+=256){ int r=i>>5, c8=(i&31)*8;
    *(uint4*)(&WfcS[r][c8]) = *(const uint4*)(WfcC + (size_t)(s*16+r)*256 + c8); }
  lwS[0][tid]=b2f(lwC[tid]); lwS[1][tid]=b2f(lwC[256+tid]); lwS[2][tid]=b2f(lwC[512+tid]);
  slotD[tid] = slotD_g[tid];
  if (tid<16) bfcS[tid] = b2f(bfcC[s*16+tid]);
  if (tid==0){ clKO[0] = (s<8)? kpad_g[s]:0; clKO[1] = (s<8)? ofs_g[s]:0; }
  for (int i=tid; i<16*264; i+=256) hS[i/264][i%264] = f2b(0.f);
  __syncthreads();
  const int kp = clKO[0], ko = clKO[1];
  if (s<8){
    for (int i=tid; i<64*104; i+=256) fMb[i/104][i%104] = f2b(0.f);
    __syncthreads();
    for (int i=tid; i<64*kp; i+=256){ int m=i/kp, k=i%kp;
      fMb[m][k] = flatMb[(size_t)m*512 + ko + k]; }
  }
  const float gw_c = (s<8)? b2f(gwC[s]) : 0.f;
  float creg[4] = {0.f,0.f,0.f,0.f};
  __syncthreads();

  for (int t=0; t<=96; ++t){
    f32x4 acc = {0,0,0,0};
    if (t<96){
#pragma unroll
      for (int rr=0; rr<4; ++rr)
        acc[rr] = __half2float(zc[((size_t)(t*128)+r0+q*4+rr)*1024 + n0 + W*16 + cl]);
    }
    if (t>0){
      gbar(barp+0, GRP*t);
      for (int i=tid; i<16*32; i+=256){ int r=i>>5, c8=(i&31)*8;
        *(uint4*)(&hS[r][c8]) = *(const uint4*)(hX + (size_t)(r0+r)*256 + c8); }
      __syncthreads();
    }
    // x_i tile (wave 0): 16 rows x 16 cols, K=256
    if (W==0){
      f32x4 xa = {0,0,0,0};
#pragma unroll
      for (int ks=0; ks<8; ++ks){
        bf16x8 a = ld_frag(&hS[cl][ks*32 + q*8]);
        bf16x8 b = ld_frag(&WfcS[cl][ks*32 + q*8]);
        xa = mfma_bf16(a, b, xa);
      }
#pragma unroll
      for (int rr=0; rr<4; ++rr){
        int row = q*4+rr;
        float v = xa[rr] + bfcS[cl];
        if (t>0){
          size_t ob = ((size_t)(r0+row)*96 + (t-1))*256 + s*16 + cl;
          if (f32) ((float*)outv)[ob] = v; else ((bf16_t*)outv)[ob] = f2b(v);
        }
        if (t<96) xiX[(size_t)(r0+row)*256 + s*16 + cl] = f2b(v);
      }
    }
    if (t==96) break;
    // gate h-part: acc += h @ Uh^T (all waves, cols W*16..)
#pragma unroll
    for (int ks=0; ks<8; ++ks){
      bf16x8 a = ld_frag(&hS[cl][ks*32 + q*8]);
      bf16x8 b = ld_frag(&Us[W*16+cl][ks*32 + q*8]);
      acc = mfma_bf16(a, b, acc);
    }
    gbar(barp+1, GRP*(t+1));            // x_i slices visible
    if (s<8){
      for (int i=tid; i<16*104; i+=256) lsp[i/104][i%104] = f2b(0.f);
      __syncthreads();
      for (int i=tid; i<16*256; i+=256){
        int r = i>>8, d = i&255;
        int sl = slotD[d] - ko;
        if (sl >= 0 && sl < kp){
          size_t zr = ((size_t)(t*128)+r0+r)*512;
          float z  = b2f(Zcat[zr + d]);
          float zp = b2f(Zcat[zr + 256 + d]);
          float xi = b2f(xiX[(size_t)(r0+r)*256 + d]);
          lsp[r][sl] = f2b(lwS[0][d]*z + lwS[1][d]*zp + lwS[2][d]*xi);
        }
      }
      __syncthreads();
      if (W==0){
        f32x4 sa[4];
#pragma unroll
        for (int nt=0;nt<4;++nt) sa[nt]=(f32x4){0,0,0,0};
        for (int ks=0; ks<(kp>>5); ++ks){
          bf16x8 a = ld_frag(&lsp[cl][ks*32 + q*8]);
#pragma unroll
          for (int nt=0;nt<4;++nt){
            bf16x8 b = ld_frag(&fMb[nt*16+cl][ks*32 + q*8]);
            sa[nt] = mfma_bf16(a, b, sa[nt]);
          }
        }
#pragma unroll
        for (int rr=0; rr<4; ++rr){
          float mx = fmaxf(fmaxf(sa[0][rr],sa[1][rr]),fmaxf(sa[2][rr],sa[3][rr]));
          mx = fmaxf(mx, __shfl_xor(mx,1));
          mx = fmaxf(mx, __shfl_xor(mx,2));
          mx = fmaxf(mx, __shfl_xor(mx,4));
          mx = fmaxf(mx, __shfl_xor(mx,8));
          float e0=expf(sa[0][rr]-mx), e1=expf(sa[1][rr]-mx);
          float e2=expf(sa[2][rr]-mx), e3=expf(sa[3][rr]-mx);
          float sm = e0+e1+e2+e3;
          sm += __shfl_xor(sm,1); sm += __shfl_xor(sm,2);
          sm += __shfl_xor(sm,4); sm += __shfl_xor(sm,8);
          float sc = gw_c / sm;
          size_t tb = (size_t)(r0+q*4+rr)*512 + s*64;
          tX[tb +  0 + cl] = f2b(e0*sc);
          tX[tb + 16 + cl] = f2b(e1*sc);
          tX[tb + 32 + cl] = f2b(e2*sc);
          tX[tb + 48 + cl] = f2b(e3*sc);
        }
      }
    }
    gbar(barp+2, GRP*(t+1));            // t slices visible
    for (int i=tid; i<16*64; i+=256){ int r=i>>6, c8=(i&63)*8;
      *(uint4*)(&tS[r][c8]) = *(const uint4*)(tX + (size_t)(r0+r)*512 + c8); }
    __syncthreads();
    // gate gd-part: acc += t @ G^T
#pragma unroll
    for (int ks=0; ks<16; ++ks){
      bf16x8 a = ld_frag(&tS[cl][ks*32 + q*8]);
      bf16x8 b = ld_frag(&Gs[W*16+cl][ks*32 + q*8]);
      acc = mfma_bf16(a, b, acc);
    }
    // LSTM update: lanes quad = (i,f,o,c) of one j
    const int base = l & ~3;
#pragma unroll
    for (int rr=0; rr<4; ++rr){
      float p = acc[rr];
      float pi = __shfl(p, base+0);
      float pf = __shfl(p, base+1);
      float po = __shfl(p, base+2);
      float pc = __shfl(p, base+3);
      float iv = 1.f/(1.f+expf(-pi));
      float fv = 1.f/(1.f+expf(-pf));
      float ov = 1.f/(1.f+expf(-po));
      float cv = tanhf(pc);
      float cn = fv*creg[rr] + iv*cv;
      creg[rr] = cn;
      float hv = ov * tanhf(cn);
      if ((l&3)==0)
        hX[(size_t)(r0+q*4+rr)*256 + s*16 + W*4 + (cl>>2)] = f2b(hv);
    }
  }
}

extern "C" void kernel_launch(void* const* d_in, const int* in_sizes, int n_in,
                              void* d_out, int out_size, void* d_ws, size_t ws_size,
                              hipStream_t stream)
{
  const void* x       = d_in[0];
  const void* Xmean   = d_in[1];
  const int*  clusters= (const int*)d_in[2];
  const void* Wi  = d_in[3];
  const void* bi  = d_in[4];
  const void* Wf  = d_in[5];
  const void* bfp = d_in[6];
  const void* Wo  = d_in[7];
  const void* bo  = d_in[8];
  const void* Wc  = d_in[9];
  const void* bcp = d_in[10];
  const void* Wfc = d_in[11];
  const void* bfc = d_in[12];
  const void* gzw = d_in[13];
  const void* gzb = d_in[14];
  const void* gzpw= d_in[15];
  const void* gzpb= d_in[16];
  const void* memory = d_in[17];
  const void* localw = d_in[18];
  const void* globalw= d_in[19];
  (void)in_sizes; (void)n_in; (void)out_size; (void)ws_size;

  char* ws = (char*)d_ws;
  size_t off = 0;
  auto take = [&](size_t bytes)->char*{
    char* p = ws + off; off = (off + bytes + 255) & ~(size_t)255; return p; };
  int*    flags  = (int*)   take(16);
  int*    bar    = (int*)   take(64*4);
  bf16_t* U      = (bf16_t*)take((size_t)1024*512*2);     // 1 MB
  bf16_t* Uz     = (bf16_t*)take((size_t)1024*512*2);     // 1 MB
  bf16_t* G      = (bf16_t*)take((size_t)1024*512*2);     // 1 MB
  bf16_t* flatMb = (bf16_t*)take((size_t)64*512*2);       // 64 KB
  bf16_t* WfcC   = (bf16_t*)take((size_t)65536*2);
  bf16_t* XmC    = (bf16_t*)take((size_t)24576*2);
  bf16_t* bfcC   = (bf16_t*)take(256*2);
  bf16_t* lwC    = (bf16_t*)take(768*2);
  bf16_t* gwC    = (bf16_t*)take(8*2);
  float*  gzC    = (float*) take(1024*4);
  float*  bias2  = (float*) take(1024*4);
  int* slotD = (int*)take(256*4);
  int* kpad  = (int*)take(8*4);
  int* ofsb  = (int*)take(8*4);
  bf16_t* hXb    = (bf16_t*)take((size_t)128*256*2);
  bf16_t* xiXb   = (bf16_t*)take((size_t)128*256*2);
  bf16_t* tXb    = (bf16_t*)take((size_t)128*512*2);
  bf16_t* Zcat   = (bf16_t*)take((size_t)12288*512*2);    // 12.6 MB
  __half* zc     = (__half*)take((size_t)12288*1024*2);   // 25.2 MB

  k_detect<<<1,    64, 0,stream>>>((const uint32_t*)x, (const uint32_t*)clusters, flags);
  k_zero  <<<1,    64, 0,stream>>>(bar);
  k_canon <<<256,  256,0,stream>>>(Wfc, Xmean, bfc, localw, globalw,
                                   gzw, gzb, gzpw, gzpb, flags,
                                   WfcC, XmC, bfcC, lwC, gwC, gzC);
  k_fold  <<<1024, 256,0,stream>>>(Wi,Wf,Wo,Wc, bi,bfp,bo,bcp, Wfc,bfc, flags,
                                   U, Uz, bias2);
  k_foldG <<<256,  256,0,stream>>>(Wi,Wf,Wo,Wc, memory, flags, G);
  k_tables<<<1,    256,0,stream>>>(clusters, memory, flags, flatMb,
                                   slotD, kpad, ofsb);
  k_zzp   <<<12288,256,0,stream>>>(x, XmC, gzC, flags, Zcat);
  k_zc    <<<dim3(96,8),256,0,stream>>>(Zcat, Uz, bias2, zc);
  k_main  <<<128,  256,0,stream>>>(flags, WfcC, bfcC, lwC, gwC, U, G, zc, Zcat,
                                   flatMb, slotD, kpad, ofsb,
                                   hXb, xiXb, tXb, bar, d_out);
}